// Round 3
// baseline (139.546 us; speedup 1.0000x reference)
//
#include <hip/hip_runtime.h>
#include <hip/hip_bf16.h>
#include <stdint.h>

// Problem shape (fixed by reference)
#define B_ 32
#define T_ 1024
#define J_ 256
#define D_ 512

typedef __attribute__((ext_vector_type(8))) short short8;   // 8 bf16 (4 VGPRs)
typedef __attribute__((ext_vector_type(4))) float floatx4;  // MFMA C/D frag

// ---------------------------------------------------------------------------
// Kernel 1: prep_u — B2[j,k] = bf16(u[j,k]*w_m[k] + w_h[k]),
//                    tu[j]   = sum_k u[j,k]*w_u[k]   (fp32)
// Identity: out[t,j] = sum_k h[t,k]*B2[j,k] + tu[j]
// ---------------------------------------------------------------------------
__global__ __launch_bounds__(256) void prep_u_kernel(
    const float* __restrict__ u, const float* __restrict__ w,
    __hip_bfloat16* __restrict__ B2, float* __restrict__ tu)
{
    int row  = blockIdx.x * 4 + (threadIdx.x >> 6);   // one wave per u-row
    int lane = threadIdx.x & 63;
    const float* src = u + (size_t)row * D_;
    int base = lane * 8;

    float4 v0  = *(const float4*)(src + base);
    float4 v1  = *(const float4*)(src + base + 4);
    float4 wh0 = *(const float4*)(w + base);            // w_h = w[0:512]
    float4 wh1 = *(const float4*)(w + base + 4);
    float4 wu0 = *(const float4*)(w + D_ + base);       // w_u = w[512:1024]
    float4 wu1 = *(const float4*)(w + D_ + base + 4);
    float4 wm0 = *(const float4*)(w + 2*D_ + base);     // w_m = w[1024:1536]
    float4 wm1 = *(const float4*)(w + 2*D_ + base + 4);

    float s = v0.x*wu0.x + v0.y*wu0.y + v0.z*wu0.z + v0.w*wu0.w
            + v1.x*wu1.x + v1.y*wu1.y + v1.z*wu1.z + v1.w*wu1.w;

    float vals[8] = {
        v0.x*wm0.x + wh0.x, v0.y*wm0.y + wh0.y,
        v0.z*wm0.z + wh0.z, v0.w*wm0.w + wh0.w,
        v1.x*wm1.x + wh1.x, v1.y*wm1.y + wh1.y,
        v1.z*wm1.z + wh1.z, v1.w*wm1.w + wh1.w };

    union { __hip_bfloat16 b[8]; uint4 q; } pk;
#pragma unroll
    for (int i = 0; i < 8; i++) pk.b[i] = __float2bfloat16(vals[i]);
    *(uint4*)(B2 + (size_t)row * D_ + base) = pk.q;     // 16B coalesced store

#pragma unroll
    for (int off = 32; off > 0; off >>= 1) s += __shfl_down(s, off, 64);
    if (lane == 0) tu[row] = s;
}

// ---------------------------------------------------------------------------
// Kernel 2: fused GEMM  out[b] = bf16(h[b]) @ B2[b]^T + tu
// 64x128 tile (1024 blocks = 4 blocks/CU), BK=32, 4 waves in 2x2, each wave
// 2x4 of 16x16x32 bf16 MFMA.
// LDS layout XOR-swizzled: element (row,cb) at row*32 + (cb^((row>>1)&3))*8
//   -> staging is lane-linear (conflict-free, and satisfies global_load_lds'
//      wave-uniform-base+lane*16 constraint); frag ds_read_b128 is 2-way
//      per lane-quarter = free (m136).
// ---------------------------------------------------------------------------
__device__ inline void gload_lds16(const void* g, void* l) {
    __builtin_amdgcn_global_load_lds(
        (__attribute__((address_space(1))) void*)(g),
        (__attribute__((address_space(3))) void*)(l),
        16, 0, 0);
}

__global__ __launch_bounds__(256) void gemm_kernel(
    const float* __restrict__ h,            // [B, T, D] fp32
    const __hip_bfloat16* __restrict__ B2,  // [B, J, D] bf16 (= u*w_m + w_h)
    const float* __restrict__ tu,           // [B*J] fp32
    float* __restrict__ out)                // [B, T, J] fp32
{
    __shared__ __align__(16) __hip_bfloat16 sA[64 * 32];    // 4 KB
    __shared__ __align__(16) __hip_bfloat16 sB[128 * 32];   // 8 KB

    const int b   = blockIdx.y;
    const int tM  = blockIdx.x >> 1;        // T/64 = 16 tiles
    const int tN  = blockIdx.x & 1;         // J/128 = 2 tiles
    const int tid = threadIdx.x;
    const int w = tid >> 6, lane = tid & 63;
    const int wr = w >> 1, wc = w & 1;      // 2x2 wave grid: 32x64 per wave

    const float*          Ah = h  + ((size_t)b * T_ + tM * 64) * D_;
    const __hip_bfloat16* Bb = B2 + ((size_t)b * J_ + tN * 128) * D_;

    // staging chunk mapping (both A and B): chunk c -> row c>>2, swizzled
    // col-block cb' = c&3 holds source cb = (c&3) ^ ((c>>3)&3)
    const int srow = tid >> 2;                        // 0..63
    const int scb  = ((tid & 3) ^ ((tid >> 3) & 3));  // source col-block
    const int ssc  = scb * 8;                         // source col (elements)
    const int ldsOff = tid * 8;                       // linear LDS chunk

    floatx4 acc[2][4];
#pragma unroll
    for (int i = 0; i < 2; i++)
#pragma unroll
        for (int j = 0; j < 4; j++) acc[i][j] = (floatx4)0.0f;

    const int cb = lane >> 4;               // frag k-block 0..3
    const int fr = lane & 15;               // m (or n) within the 16-tile

    for (int k0 = 0; k0 < D_; k0 += 32) {
        // async bf16 B staging: 128x32 = 512 chunks = 2 issues/thread
        gload_lds16(Bb + (size_t)srow        * D_ + k0 + ssc, sB + ldsOff);
        gload_lds16(Bb + (size_t)(srow + 64) * D_ + k0 + ssc, sB + 64 * 32 + ldsOff);

        // A: 64x32 fp32 -> bf16, 1 chunk/thread, lane-linear ds_write_b128
        {
            const float* ap = Ah + (size_t)srow * D_ + k0 + ssc;
            float4 a0 = *(const float4*)(ap);
            float4 a1 = *(const float4*)(ap + 4);
            union { __hip_bfloat16 b[8]; uint4 q; } pk;
            pk.b[0]=__float2bfloat16(a0.x); pk.b[1]=__float2bfloat16(a0.y);
            pk.b[2]=__float2bfloat16(a0.z); pk.b[3]=__float2bfloat16(a0.w);
            pk.b[4]=__float2bfloat16(a1.x); pk.b[5]=__float2bfloat16(a1.y);
            pk.b[6]=__float2bfloat16(a1.z); pk.b[7]=__float2bfloat16(a1.w);
            *(uint4*)(sA + ldsOff) = pk.q;
        }
        __syncthreads();   // drains vmcnt (async B) + lgkm (A ds_write)

        short8 af[2], bfr[4];
#pragma unroll
        for (int mi = 0; mi < 2; mi++) {
            int rr = wr * 32 + mi * 16 + fr;
            af[mi] = *(const short8*)(sA + rr * 32 + ((cb ^ ((rr >> 1) & 3)) << 3));
        }
#pragma unroll
        for (int ni = 0; ni < 4; ni++) {
            int rr = wc * 64 + ni * 16 + fr;
            bfr[ni] = *(const short8*)(sB + rr * 32 + ((cb ^ ((rr >> 1) & 3)) << 3));
        }
#pragma unroll
        for (int mi = 0; mi < 2; mi++)
#pragma unroll
            for (int ni = 0; ni < 4; ni++)
                acc[mi][ni] = __builtin_amdgcn_mfma_f32_16x16x32_bf16(
                    af[mi], bfr[ni], acc[mi][ni], 0, 0, 0);
        __syncthreads();
    }

    // epilogue: C/D layout col = lane&15, row = (lane>>4)*4 + reg  [m89/m91]
    const size_t outB = (size_t)b * T_ * J_;
    const int colq = lane & 15;
    const int rq   = (lane >> 4) * 4;
    const float* tub = tu + b * J_;
#pragma unroll
    for (int mi = 0; mi < 2; mi++) {
        int r0 = tM * 64 + wr * 32 + mi * 16 + rq;
#pragma unroll
        for (int ni = 0; ni < 4; ni++) {
            int col = tN * 128 + wc * 64 + ni * 16 + colq;
            float tuv = tub[col];
#pragma unroll
            for (int r = 0; r < 4; r++) {
                out[outB + (size_t)(r0 + r) * J_ + col] =
                    acc[mi][ni][r] + tuv;
            }
        }
    }
}

// ---------------------------------------------------------------------------
extern "C" void kernel_launch(void* const* d_in, const int* in_sizes, int n_in,
                              void* d_out, int out_size, void* d_ws, size_t ws_size,
                              hipStream_t stream)
{
    const float* h = (const float*)d_in[0];
    const float* u = (const float*)d_in[1];
    const float* w = (const float*)d_in[2];
    float* out = (float*)d_out;

    uint8_t* ws = (uint8_t*)d_ws;
    __hip_bfloat16* B2 = (__hip_bfloat16*)ws;                 // 8 MiB
    float* tu = (float*)(ws + (size_t)B_ * J_ * D_ * 2);      // 32 KiB

    // one wave per u-row; 4 rows per 256-thread block; 8192 rows total
    prep_u_kernel<<<dim3(B_ * J_ / 4), 256, 0, stream>>>(u, w, B2, tu);

    // 64x128 output tiles: (T/64)*(J/128)=32 tiles/batch, 32 batches
    gemm_kernel<<<dim3((T_ / 64) * (J_ / 128), B_), 256, 0, stream>>>(h, B2, tu, out);
}

// Round 4
// 131.707 us; speedup vs baseline: 1.0595x; 1.0595x over previous
//
#include <hip/hip_runtime.h>
#include <hip/hip_bf16.h>
#include <stdint.h>

// Problem shape (fixed by reference)
#define B_ 32
#define T_ 1024
#define J_ 256
#define D_ 512

typedef __attribute__((ext_vector_type(8))) short short8;   // 8 bf16 (4 VGPRs)
typedef __attribute__((ext_vector_type(4))) float floatx4;  // MFMA C/D frag

// ---------------------------------------------------------------------------
// Kernel 1: prep_u — B2[j,k] = bf16(u[j,k]*w_m[k] + w_h[k]),
//                    tu[j]   = sum_k u[j,k]*w_u[k]   (fp32)
// Identity: out[t,j] = sum_k h[t,k]*B2[j,k] + tu[j]
// ---------------------------------------------------------------------------
__global__ __launch_bounds__(256) void prep_u_kernel(
    const float* __restrict__ u, const float* __restrict__ w,
    __hip_bfloat16* __restrict__ B2, float* __restrict__ tu)
{
    int row  = blockIdx.x * 4 + (threadIdx.x >> 6);   // one wave per u-row
    int lane = threadIdx.x & 63;
    const float* src = u + (size_t)row * D_;
    int base = lane * 8;

    float4 v0  = *(const float4*)(src + base);
    float4 v1  = *(const float4*)(src + base + 4);
    float4 wh0 = *(const float4*)(w + base);            // w_h = w[0:512]
    float4 wh1 = *(const float4*)(w + base + 4);
    float4 wu0 = *(const float4*)(w + D_ + base);       // w_u = w[512:1024]
    float4 wu1 = *(const float4*)(w + D_ + base + 4);
    float4 wm0 = *(const float4*)(w + 2*D_ + base);     // w_m = w[1024:1536]
    float4 wm1 = *(const float4*)(w + 2*D_ + base + 4);

    float s = v0.x*wu0.x + v0.y*wu0.y + v0.z*wu0.z + v0.w*wu0.w
            + v1.x*wu1.x + v1.y*wu1.y + v1.z*wu1.z + v1.w*wu1.w;

    float vals[8] = {
        v0.x*wm0.x + wh0.x, v0.y*wm0.y + wh0.y,
        v0.z*wm0.z + wh0.z, v0.w*wm0.w + wh0.w,
        v1.x*wm1.x + wh1.x, v1.y*wm1.y + wh1.y,
        v1.z*wm1.z + wh1.z, v1.w*wm1.w + wh1.w };

    union { __hip_bfloat16 b[8]; uint4 q; } pk;
#pragma unroll
    for (int i = 0; i < 8; i++) pk.b[i] = __float2bfloat16(vals[i]);
    *(uint4*)(B2 + (size_t)row * D_ + base) = pk.q;     // 16B coalesced store

#pragma unroll
    for (int off = 32; off > 0; off >>= 1) s += __shfl_down(s, off, 64);
    if (lane == 0) tu[row] = s;
}

// ---------------------------------------------------------------------------
// Kernel 2: fused GEMM  out[b] = bf16(h[b]) @ B2[b]^T + tu
//
// Barrier-free K-loop structure:
//  - 128x128 tile, 512 threads (8 waves), wave w owns rows w*16..w*16+15.
//  - B2 (bf16) staged to LDS in 2 phases of K=256 (64 KB), XOR-swizzled.
//  - A (= h, fp32) is NEVER staged: each lane loads its exact MFMA fragment
//    (8 fp32 = 2 dwordx4) straight from global and converts to bf16 in regs.
//  - Inside a phase: 8 k-steps with NO __syncthreads — A loads pipeline
//    across k-steps (the round-3 bottleneck was barrier-quantized MLP).
// LDS chunk map: (j, c) [c = k-chunk of 8 elems, 0..31 within phase] lives at
//   chunk index j*32 + (c ^ (j&31))  -> staging is lane-linear (required by
//   global_load_lds), frag reads are 2-way per quarter = free (m136).
// ---------------------------------------------------------------------------
__device__ inline void gload_lds16(const void* g, void* l) {
    __builtin_amdgcn_global_load_lds(
        (__attribute__((address_space(1))) void*)(g),
        (__attribute__((address_space(3))) void*)(l),
        16, 0, 0);
}

__global__ __launch_bounds__(512, 4) void gemm_kernel(
    const float* __restrict__ h,            // [B, T, D] fp32
    const __hip_bfloat16* __restrict__ B2,  // [B, J, D] bf16 (= u*w_m + w_h)
    const float* __restrict__ tu,           // [B*J] fp32
    float* __restrict__ out)                // [B, T, J] fp32
{
    __shared__ __align__(16) __hip_bfloat16 sB[128 * 256];  // 64 KB

    const int b   = blockIdx.y;
    const int tM  = blockIdx.x >> 1;        // T/128 = 8 tiles
    const int tN  = blockIdx.x & 1;         // J/128 = 2 tiles
    const int tid = threadIdx.x;
    const int w = tid >> 6, lane = tid & 63;

    const int fr = lane & 15;               // row within 16-tile (m or n)
    const int kq = lane >> 4;               // k-quarter 0..3

    // this wave's 16 A-rows; lane reads row fr
    const float* Aw = h + ((size_t)b * T_ + tM * 128 + w * 16 + fr) * D_;
    const __hip_bfloat16* Bb = B2 + ((size_t)b * J_ + tN * 128) * D_;

    floatx4 acc[8];
#pragma unroll
    for (int n = 0; n < 8; n++) acc[n] = (floatx4)0.0f;

    for (int p = 0; p < 2; p++) {
        // ---- stage B phase: 128 rows x 256 k = 4096 chunks, 8 per thread
#pragma unroll
        for (int i = 0; i < 8; i++) {
            int q  = i * 512 + tid;         // lane-linear LDS chunk
            int j  = q >> 5;
            int c  = (q & 31) ^ (j & 31);   // source k-chunk (XOR swizzle)
            gload_lds16(Bb + (size_t)j * D_ + p * 256 + c * 8, sB + q * 8);
        }
        __syncthreads();                    // drains vmcnt, B tile ready

        // ---- 8 k-steps, NO barriers: A loads pipeline freely
#pragma unroll
        for (int ks = 0; ks < 8; ks++) {
            const float* ap = Aw + p * 256 + ks * 32 + kq * 8;
            float4 a0 = *(const float4*)(ap);
            float4 a1 = *(const float4*)(ap + 4);
            union { __hip_bfloat16 e[8]; short8 v; } af;
            af.e[0]=__float2bfloat16(a0.x); af.e[1]=__float2bfloat16(a0.y);
            af.e[2]=__float2bfloat16(a0.z); af.e[3]=__float2bfloat16(a0.w);
            af.e[4]=__float2bfloat16(a1.x); af.e[5]=__float2bfloat16(a1.y);
            af.e[6]=__float2bfloat16(a1.z); af.e[7]=__float2bfloat16(a1.w);
#pragma unroll
            for (int n = 0; n < 8; n++) {
                int j = n * 16 + fr;
                int c = ks * 4 + kq;
                short8 bf = *(const short8*)(sB + ((j * 32) + (c ^ (j & 31))) * 8);
                acc[n] = __builtin_amdgcn_mfma_f32_16x16x32_bf16(
                    af.v, bf, acc[n], 0, 0, 0);
            }
        }
        __syncthreads();                    // waves done reading sB (phase 0)
    }

    // epilogue: C/D layout col = lane&15, row = (lane>>4)*4 + reg  [m89/m91]
    const size_t outB = (size_t)b * T_ * J_;
    const int r0 = tM * 128 + w * 16 + (lane >> 4) * 4;
    const float* tub = tu + b * J_;
#pragma unroll
    for (int n = 0; n < 8; n++) {
        int col = tN * 128 + n * 16 + fr;
        float tuv = tub[col];
#pragma unroll
        for (int r = 0; r < 4; r++) {
            out[outB + (size_t)(r0 + r) * J_ + col] = acc[n][r] + tuv;
        }
    }
}

// ---------------------------------------------------------------------------
extern "C" void kernel_launch(void* const* d_in, const int* in_sizes, int n_in,
                              void* d_out, int out_size, void* d_ws, size_t ws_size,
                              hipStream_t stream)
{
    const float* h = (const float*)d_in[0];
    const float* u = (const float*)d_in[1];
    const float* w = (const float*)d_in[2];
    float* out = (float*)d_out;

    uint8_t* ws = (uint8_t*)d_ws;
    __hip_bfloat16* B2 = (__hip_bfloat16*)ws;                 // 8 MiB
    float* tu = (float*)(ws + (size_t)B_ * J_ * D_ * 2);      // 32 KiB

    // one wave per u-row; 4 rows per 256-thread block; 8192 rows total
    prep_u_kernel<<<dim3(B_ * J_ / 4), 256, 0, stream>>>(u, w, B2, tu);

    // 128x128 output tiles: (T/128)*(J/128)=16 tiles/batch, 32 batches
    gemm_kernel<<<dim3((T_ / 128) * (J_ / 128), B_), 512, 0, stream>>>(h, B2, tu, out);
}

// Round 5
// 129.558 us; speedup vs baseline: 1.0771x; 1.0166x over previous
//
#include <hip/hip_runtime.h>
#include <hip/hip_bf16.h>
#include <stdint.h>

// Problem shape (fixed by reference)
#define B_ 32
#define T_ 1024
#define J_ 256
#define D_ 512

typedef __attribute__((ext_vector_type(8))) short short8;   // 8 bf16 (4 VGPRs)
typedef __attribute__((ext_vector_type(4))) float floatx4;  // MFMA C/D frag

// ---------------------------------------------------------------------------
// Kernel 1: prep_u — B2[j,k] = bf16(u[j,k]*w_m[k] + w_h[k]),
//                    tu[j]   = sum_k u[j,k]*w_u[k]   (fp32)
// Identity: out[t,j] = sum_k h[t,k]*B2[j,k] + tu[j]
// ---------------------------------------------------------------------------
__global__ __launch_bounds__(256) void prep_u_kernel(
    const float* __restrict__ u, const float* __restrict__ w,
    __hip_bfloat16* __restrict__ B2, float* __restrict__ tu)
{
    int row  = blockIdx.x * 4 + (threadIdx.x >> 6);   // one wave per u-row
    int lane = threadIdx.x & 63;
    const float* src = u + (size_t)row * D_;
    int base = lane * 8;

    float4 v0  = *(const float4*)(src + base);
    float4 v1  = *(const float4*)(src + base + 4);
    float4 wh0 = *(const float4*)(w + base);            // w_h = w[0:512]
    float4 wh1 = *(const float4*)(w + base + 4);
    float4 wu0 = *(const float4*)(w + D_ + base);       // w_u = w[512:1024]
    float4 wu1 = *(const float4*)(w + D_ + base + 4);
    float4 wm0 = *(const float4*)(w + 2*D_ + base);     // w_m = w[1024:1536]
    float4 wm1 = *(const float4*)(w + 2*D_ + base + 4);

    float s = v0.x*wu0.x + v0.y*wu0.y + v0.z*wu0.z + v0.w*wu0.w
            + v1.x*wu1.x + v1.y*wu1.y + v1.z*wu1.z + v1.w*wu1.w;

    float vals[8] = {
        v0.x*wm0.x + wh0.x, v0.y*wm0.y + wh0.y,
        v0.z*wm0.z + wh0.z, v0.w*wm0.w + wh0.w,
        v1.x*wm1.x + wh1.x, v1.y*wm1.y + wh1.y,
        v1.z*wm1.z + wh1.z, v1.w*wm1.w + wh1.w };

    union { __hip_bfloat16 b[8]; uint4 q; } pk;
#pragma unroll
    for (int i = 0; i < 8; i++) pk.b[i] = __float2bfloat16(vals[i]);
    *(uint4*)(B2 + (size_t)row * D_ + base) = pk.q;     // 16B coalesced store

#pragma unroll
    for (int off = 32; off > 0; off >>= 1) s += __shfl_down(s, off, 64);
    if (lane == 0) tu[row] = s;
}

// ---------------------------------------------------------------------------
// Kernel 2: fused GEMM  out[b] = bf16(h[b]) @ B2[b]^T + tu
//
// Round-5 structure (dbuf + full-J tile):
//  - 128x256 tile (full J): each h row read by exactly ONE block.
//  - 1024 threads = 16 waves, wave grid 8x2: wave owns 16 rows x 128 cols.
//  - K in 4 phases of 128; B2 phase tile = 256x128 bf16 = 64 KB, double
//    buffered (128 KB LDS). Phase p+1 is staged (async global_load_lds,
//    no wait) BEFORE computing phase p, so the vmcnt(0) drain at the
//    end-of-phase barrier is free — loads had the whole phase to land.
//  - A (= h, fp32) never staged: each lane loads its exact MFMA fragment
//    (2 x dwordx4) from global and converts to bf16 in regs; no barriers
//    between k-steps, so A loads pipeline continuously.
// LDS chunk map: (j, c) [c = 8-elem k-chunk, 0..15 per phase] at chunk
//   j*16 + (c ^ (j&15))  -> staging lane-linear (global_load_lds legal,
//   conflict-free); frag ds_read_b128 2-way per quarter = free (m136).
// ---------------------------------------------------------------------------
__device__ inline void gload_lds16(const void* g, void* l) {
    __builtin_amdgcn_global_load_lds(
        (__attribute__((address_space(1))) void*)(g),
        (__attribute__((address_space(3))) void*)(l),
        16, 0, 0);
}

__global__ __launch_bounds__(1024, 4) void gemm_kernel(
    const float* __restrict__ h,            // [B, T, D] fp32
    const __hip_bfloat16* __restrict__ B2,  // [B, J, D] bf16 (= u*w_m + w_h)
    const float* __restrict__ tu,           // [B*J] fp32
    float* __restrict__ out)                // [B, T, J] fp32
{
    __shared__ __align__(16) __hip_bfloat16 sB[2][256 * 128];  // 2 x 64 KB

    const int b   = blockIdx.y;
    const int tM  = blockIdx.x;             // T/128 = 8 tiles
    const int tid = threadIdx.x;
    const int w = tid >> 6, lane = tid & 63;
    const int wr = w >> 1, wc = w & 1;      // 8x2 wave grid

    const int fr = lane & 15;               // row within 16-tile (m or n)
    const int kq = lane >> 4;               // k-quarter 0..3

    // this wave's 16 A-rows; lane reads row fr
    const float* Aw = h + ((size_t)b * T_ + tM * 128 + wr * 16 + fr) * D_;
    const __hip_bfloat16* Bb = B2 + (size_t)b * J_ * D_;

    floatx4 acc[8];
#pragma unroll
    for (int n = 0; n < 8; n++) acc[n] = (floatx4)0.0f;

    // ---- stage phase 0 into buffer 0 (4096 chunks, 4 per thread)
#pragma unroll
    for (int i = 0; i < 4; i++) {
        int q = i * 1024 + tid;             // lane-linear LDS chunk
        int j = q >> 4;
        int c = (q & 15) ^ (j & 15);        // source k-chunk (XOR swizzle)
        gload_lds16(Bb + (size_t)j * D_ + c * 8, &sB[0][q * 8]);
    }
    __syncthreads();

    for (int p = 0; p < 4; p++) {
        // ---- prefetch phase p+1 into the other buffer (no wait here)
        if (p < 3) {
#pragma unroll
            for (int i = 0; i < 4; i++) {
                int q = i * 1024 + tid;
                int j = q >> 4;
                int c = (q & 15) ^ (j & 15);
                gload_lds16(Bb + (size_t)j * D_ + (p + 1) * 128 + c * 8,
                            &sB[(p + 1) & 1][q * 8]);
            }
        }
        const __hip_bfloat16* sBp = sB[p & 1];

        // ---- 4 k-steps, NO barriers: A loads pipeline freely
#pragma unroll
        for (int ks = 0; ks < 4; ks++) {
            const float* ap = Aw + p * 128 + ks * 32 + kq * 8;
            float4 a0 = *(const float4*)(ap);
            float4 a1 = *(const float4*)(ap + 4);
            union { __hip_bfloat16 e[8]; short8 v; } af;
            af.e[0]=__float2bfloat16(a0.x); af.e[1]=__float2bfloat16(a0.y);
            af.e[2]=__float2bfloat16(a0.z); af.e[3]=__float2bfloat16(a0.w);
            af.e[4]=__float2bfloat16(a1.x); af.e[5]=__float2bfloat16(a1.y);
            af.e[6]=__float2bfloat16(a1.z); af.e[7]=__float2bfloat16(a1.w);
#pragma unroll
            for (int n = 0; n < 8; n++) {
                int j = wc * 128 + n * 16 + fr;
                int c = ks * 4 + kq;
                short8 bf = *(const short8*)(sBp + (j * 16 + (c ^ (j & 15))) * 8);
                acc[n] = __builtin_amdgcn_mfma_f32_16x16x32_bf16(
                    af.v, bf, acc[n], 0, 0, 0);
            }
        }
        __syncthreads();   // phase handoff: drain is ~free (loads aged a phase)
    }

    // epilogue: C/D layout col = lane&15, row = (lane>>4)*4 + reg  [m89/m91]
    const size_t outB = (size_t)b * T_ * J_;
    const int r0 = tM * 128 + wr * 16 + (lane >> 4) * 4;
    const float* tub = tu + b * J_;
#pragma unroll
    for (int n = 0; n < 8; n++) {
        int col = wc * 128 + n * 16 + fr;
        float tuv = tub[col];
#pragma unroll
        for (int r = 0; r < 4; r++) {
            out[outB + (size_t)(r0 + r) * J_ + col] = acc[n][r] + tuv;
        }
    }
}

// ---------------------------------------------------------------------------
extern "C" void kernel_launch(void* const* d_in, const int* in_sizes, int n_in,
                              void* d_out, int out_size, void* d_ws, size_t ws_size,
                              hipStream_t stream)
{
    const float* h = (const float*)d_in[0];
    const float* u = (const float*)d_in[1];
    const float* w = (const float*)d_in[2];
    float* out = (float*)d_out;

    uint8_t* ws = (uint8_t*)d_ws;
    __hip_bfloat16* B2 = (__hip_bfloat16*)ws;                 // 8 MiB
    float* tu = (float*)(ws + (size_t)B_ * J_ * D_ * 2);      // 32 KiB

    // one wave per u-row; 4 rows per 256-thread block; 8192 rows total
    prep_u_kernel<<<dim3(B_ * J_ / 4), 256, 0, stream>>>(u, w, B2, tu);

    // 128x256 tiles (full J): T/128 = 8 tiles/batch, 32 batches = 256 blocks
    gemm_kernel<<<dim3(T_ / 128, B_), 1024, 0, stream>>>(h, B2, tu, out);
}